// Round 1
// baseline (1114.912 us; speedup 1.0000x reference)
//
#include <hip/hip_runtime.h>
#include <math.h>

#define L_SEQ   2048
#define BATCH_N 8
#define H_DIM   1024
#define P_DIM   512
#define M_DIM   (BATCH_N * L_SEQ)   // 16384
#define N2      1024                // packed complex width (re | im)

// ---------------------------------------------------------------------------
// Setup: per-p discretization constants.
// lam buffer layout: [lam_re(512) | lam_im(512) | g_re(512) | g_im(512)]
// ---------------------------------------------------------------------------
__global__ void setup_lam(const float* __restrict__ Lre_in,
                          const float* __restrict__ Lim_in,
                          const float* __restrict__ log_step,
                          float* __restrict__ lam) {
    int p = blockIdx.x * blockDim.x + threadIdx.x;
    if (p >= P_DIM) return;
    float step = expf(log_step[p]);          // STEP_RESCALE == 1
    float c = Lre_in[p];                     // -0.5
    float d = Lim_in[p];                     // pi * p
    float mag = expf(c * step);
    float ang = d * step;
    float lr = mag * cosf(ang);
    float li = mag * sinf(ang);
    // gamma = (Lambda_bar - 1) / Lambda
    float a = lr - 1.0f, b = li;
    float inv = 1.0f / (c * c + d * d);
    float gre = (a * c + b * d) * inv;
    float gim = (b * c - a * d) * inv;
    lam[p]             = lr;
    lam[P_DIM + p]     = li;
    lam[2 * P_DIM + p] = gre;
    lam[3 * P_DIM + p] = gim;
}

// W1[n][k]: n<512 -> B_bar_re[n][k], n>=512 -> B_bar_im[n-512][k]   (N2 x H)
__global__ void build_W1(const float* __restrict__ B,
                         const float* __restrict__ lam,
                         float* __restrict__ W1) {
    int idx = blockIdx.x * blockDim.x + threadIdx.x;   // over P*H
    if (idx >= P_DIM * H_DIM) return;
    int p = idx >> 10;            // / H_DIM
    int h = idx & (H_DIM - 1);
    float bre = B[(size_t)idx * 2];
    float bim = B[(size_t)idx * 2 + 1];
    float gre = lam[2 * P_DIM + p];
    float gim = lam[3 * P_DIM + p];
    W1[(size_t)p * H_DIM + h]           = gre * bre - gim * bim;
    W1[(size_t)(P_DIM + p) * H_DIM + h] = gre * bim + gim * bre;
}

// W2[h][k]: k<512 -> 2*C_re[h][k], k>=512 -> -2*C_im[h][k-512]   (H x N2)
__global__ void build_W2(const float* __restrict__ C,
                         float* __restrict__ W2) {
    int idx = blockIdx.x * blockDim.x + threadIdx.x;   // over H*P
    if (idx >= H_DIM * P_DIM) return;
    int h = idx >> 9;             // / P_DIM
    int p = idx & (P_DIM - 1);
    float cre = C[(size_t)idx * 2];
    float cim = C[(size_t)idx * 2 + 1];
    W2[(size_t)h * N2 + p]         =  2.0f * cre;
    W2[(size_t)h * N2 + P_DIM + p] = -2.0f * cim;
}

// ---------------------------------------------------------------------------
// FP32 tiled GEMM: Out[m][n] = sum_k A[m][k] * W[n][k]  (+ Dvec[n]*Sig[m][n])
// A: M x K row-major,  W: N x K row-major,  Out: M x N2 row-major.
// Tile 128x128, BK=16, 256 threads, 8x8 per thread as 2x2 blocks of 4x4.
// ---------------------------------------------------------------------------
__global__ __launch_bounds__(256) void gemm128(
    const float* __restrict__ A, const float* __restrict__ W,
    float* __restrict__ Out, int K,
    const float* __restrict__ Dvec, const float* __restrict__ Sig)
{
    __shared__ float As[16][132];   // [k][m], stride 132 breaks store conflicts
    __shared__ float Ws[16][132];   // [k][n]
    const int tid = threadIdx.x;
    const int m0 = blockIdx.y * 128;
    const int n0 = blockIdx.x * 128;
    const int tx = tid & 15;        // n micro index
    const int ty = tid >> 4;        // m micro index
    const int lr = tid >> 2;        // load row 0..63
    const int lc = (tid & 3) << 2;  // load col 0,4,8,12

    float acc[2][2][4][4] = {};

    const float* Aptr = A + (size_t)(m0 + lr) * K + lc;
    const float* Wptr = W + (size_t)(n0 + lr) * K + lc;

    for (int k0 = 0; k0 < K; k0 += 16) {
        float4 a0 = *(const float4*)(Aptr + k0);
        float4 a1 = *(const float4*)(Aptr + (size_t)64 * K + k0);
        float4 w0 = *(const float4*)(Wptr + k0);
        float4 w1 = *(const float4*)(Wptr + (size_t)64 * K + k0);
        __syncthreads();   // previous iteration's LDS reads done
        As[lc + 0][lr] = a0.x; As[lc + 1][lr] = a0.y;
        As[lc + 2][lr] = a0.z; As[lc + 3][lr] = a0.w;
        As[lc + 0][lr + 64] = a1.x; As[lc + 1][lr + 64] = a1.y;
        As[lc + 2][lr + 64] = a1.z; As[lc + 3][lr + 64] = a1.w;
        Ws[lc + 0][lr] = w0.x; Ws[lc + 1][lr] = w0.y;
        Ws[lc + 2][lr] = w0.z; Ws[lc + 3][lr] = w0.w;
        Ws[lc + 0][lr + 64] = w1.x; Ws[lc + 1][lr + 64] = w1.y;
        Ws[lc + 2][lr + 64] = w1.z; Ws[lc + 3][lr + 64] = w1.w;
        __syncthreads();
        #pragma unroll
        for (int k = 0; k < 16; ++k) {
            float4 av0 = *(const float4*)&As[k][ty * 4];
            float4 av1 = *(const float4*)&As[k][ty * 4 + 64];
            float4 wv0 = *(const float4*)&Ws[k][tx * 4];
            float4 wv1 = *(const float4*)&Ws[k][tx * 4 + 64];
            const float* ap0 = (const float*)&av0;
            const float* ap1 = (const float*)&av1;
            const float* wp0 = (const float*)&wv0;
            const float* wp1 = (const float*)&wv1;
            #pragma unroll
            for (int r = 0; r < 4; ++r) {
                #pragma unroll
                for (int c = 0; c < 4; ++c) {
                    acc[0][0][r][c] = fmaf(ap0[r], wp0[c], acc[0][0][r][c]);
                    acc[0][1][r][c] = fmaf(ap0[r], wp1[c], acc[0][1][r][c]);
                    acc[1][0][r][c] = fmaf(ap1[r], wp0[c], acc[1][0][r][c]);
                    acc[1][1][r][c] = fmaf(ap1[r], wp1[c], acc[1][1][r][c]);
                }
            }
        }
    }

    #pragma unroll
    for (int mi = 0; mi < 2; ++mi) {
        #pragma unroll
        for (int r = 0; r < 4; ++r) {
            int row = m0 + ty * 4 + mi * 64 + r;
            #pragma unroll
            for (int ni = 0; ni < 2; ++ni) {
                int col0 = n0 + tx * 4 + ni * 64;
                float4 v;
                float* vp = (float*)&v;
                #pragma unroll
                for (int c = 0; c < 4; ++c) {
                    float val = acc[mi][ni][r][c];
                    if (Dvec) {
                        val = fmaf(Dvec[col0 + c],
                                   Sig[(size_t)row * N2 + col0 + c], val);
                    }
                    vp[c] = val;
                }
                *(float4*)(Out + (size_t)row * N2 + col0) = v;
            }
        }
    }
}

// ---------------------------------------------------------------------------
// Sequential scan over L, in place on Bu (read-before-write per element).
// x_l = lam * x_{l-1} + u_l (complex), x_{-1} = 0 (prev_state never reaches
// the b-component of the associative scan).
// Grid: BATCH_N blocks x 512 threads (one thread per p).
// ---------------------------------------------------------------------------
__global__ __launch_bounds__(512) void scan_kernel(
    const float* __restrict__ lam, float* __restrict__ BuXS,
    float* __restrict__ out_state, int interleaved)
{
    int b = blockIdx.x;
    int p = threadIdx.x;
    float lr = lam[p];
    float li = lam[P_DIM + p];
    float xr = 0.0f, xi = 0.0f;
    float* base = BuXS + (size_t)b * L_SEQ * N2;
    for (int l0 = 0; l0 < L_SEQ; l0 += 16) {
        float ur[16], ui[16];
        #pragma unroll
        for (int j = 0; j < 16; ++j) {
            ur[j] = base[(size_t)(l0 + j) * N2 + p];
            ui[j] = base[(size_t)(l0 + j) * N2 + P_DIM + p];
        }
        #pragma unroll
        for (int j = 0; j < 16; ++j) {
            float nr = fmaf(lr, xr, fmaf(-li, xi, ur[j]));
            float ni = fmaf(lr, xi, fmaf(li, xr, ui[j]));
            xr = nr; xi = ni;
            ur[j] = nr; ui[j] = ni;
        }
        #pragma unroll
        for (int j = 0; j < 16; ++j) {
            base[(size_t)(l0 + j) * N2 + p]         = ur[j];
            base[(size_t)(l0 + j) * N2 + P_DIM + p] = ui[j];
        }
    }
    if (interleaved) {
        out_state[((size_t)b * P_DIM + p) * 2]     = xr;
        out_state[((size_t)b * P_DIM + p) * 2 + 1] = xi;
    } else {
        out_state[(size_t)b * P_DIM + p] = xr;
    }
}

// ---------------------------------------------------------------------------
extern "C" void kernel_launch(void* const* d_in, const int* in_sizes, int n_in,
                              void* d_out, int out_size, void* d_ws, size_t ws_size,
                              hipStream_t stream)
{
    const float* signal   = (const float*)d_in[0];
    // d_in[1] = prev_state: provably does not affect outputs (see scan note)
    const float* Lre      = (const float*)d_in[2];
    const float* Lim      = (const float*)d_in[3];
    const float* B        = (const float*)d_in[4];
    const float* C        = (const float*)d_in[5];
    const float* Dv       = (const float*)d_in[6];
    const float* log_step = (const float*)d_in[7];

    // ws layout (floats): W1 (1024*1024) | W2 (1024*1024) | lam (2048) | Bu/XS (16384*1024)
    float* W1  = (float*)d_ws;
    float* W2  = W1 + (size_t)N2 * H_DIM;
    float* lam = W2 + (size_t)H_DIM * N2;
    float* Bu  = lam + 4 * P_DIM;
    size_t need = ((size_t)N2 * H_DIM + (size_t)H_DIM * N2 + 4 * P_DIM
                   + (size_t)M_DIM * N2) * sizeof(float);
    if (ws_size < need) return;  // visible clean failure rather than corruption

    float* y_out = (float*)d_out;
    float* state_out = y_out + (size_t)M_DIM * H_DIM;
    int interleaved = (out_size - M_DIM * H_DIM) >= 2 * BATCH_N * P_DIM;

    setup_lam<<<dim3(2), dim3(256), 0, stream>>>(Lre, Lim, log_step, lam);
    build_W1<<<dim3((P_DIM * H_DIM) / 256), dim3(256), 0, stream>>>(B, lam, W1);
    build_W2<<<dim3((H_DIM * P_DIM) / 256), dim3(256), 0, stream>>>(C, W2);

    // GEMM1: Bu[m][n] = sum_h signal[m][h] * W1[n][h]
    gemm128<<<dim3(N2 / 128, M_DIM / 128), dim3(256), 0, stream>>>(
        signal, W1, Bu, H_DIM, nullptr, nullptr);

    // scan along L (in place), also emits final state
    scan_kernel<<<dim3(BATCH_N), dim3(512), 0, stream>>>(
        lam, Bu, state_out, interleaved);

    // GEMM2: y[m][h] = sum_k XS[m][k] * W2[h][k] + D[h]*signal[m][h]
    gemm128<<<dim3(N2 / 128, M_DIM / 128), dim3(256), 0, stream>>>(
        Bu, W2, y_out, N2, Dv, signal);
}

// Round 2
// 291.101 us; speedup vs baseline: 3.8300x; 3.8300x over previous
//
#include <hip/hip_runtime.h>
#include <math.h>

#define L_SEQ   2048
#define BATCH_N 8
#define H_DIM   1024
#define P_DIM   512
#define M_DIM   (BATCH_N * L_SEQ)   // 16384
#define N2      1024                // packed complex width (re | im)
#define NC      16                  // scan chunks
#define T_CHUNK 128                 // L_SEQ / NC

typedef __attribute__((ext_vector_type(8))) __bf16 bf16x8;
typedef __attribute__((ext_vector_type(4))) float f32x4;

__device__ __forceinline__ unsigned f2bf_bits(float f) {
    unsigned u = __builtin_bit_cast(unsigned, f);
    return (u + 0x7fffu + ((u >> 16) & 1u)) >> 16;   // RNE
}
__device__ __forceinline__ float bf_lo(unsigned v) {
    return __builtin_bit_cast(float, v << 16);
}
__device__ __forceinline__ float bf_hi(unsigned v) {
    return __builtin_bit_cast(float, v & 0xffff0000u);
}

#define ASYNC_COPY16(gsrc, ldst)                                            \
    __builtin_amdgcn_global_load_lds(                                       \
        (__attribute__((address_space(1))) void*)(gsrc),                    \
        (__attribute__((address_space(3))) void*)(ldst), 16, 0, 0)

// ---------------------------------------------------------------------------
// lam buffer: [lam_re(512) | lam_im(512) | g_re(512) | g_im(512)]  (fp32)
// ---------------------------------------------------------------------------
__global__ void setup_lam(const float* __restrict__ Lre_in,
                          const float* __restrict__ Lim_in,
                          const float* __restrict__ log_step,
                          float* __restrict__ lam) {
    int p = blockIdx.x * blockDim.x + threadIdx.x;
    if (p >= P_DIM) return;
    float step = expf(log_step[p]);
    float c = Lre_in[p];
    float d = Lim_in[p];
    float mag = expf(c * step);
    float ang = d * step;
    float lr = mag * cosf(ang);
    float li = mag * sinf(ang);
    float a = lr - 1.0f, b = li;
    float inv = 1.0f / (c * c + d * d);
    lam[p]             = lr;
    lam[P_DIM + p]     = li;
    lam[2 * P_DIM + p] = (a * c + b * d) * inv;   // g_re
    lam[3 * P_DIM + p] = (b * c - a * d) * inv;   // g_im
}

// W1[n][k] bf16: n<512 -> B_bar_re[n][k], n>=512 -> B_bar_im  (N2 x H)
__global__ void build_W1(const float* __restrict__ B,
                         const float* __restrict__ lam,
                         unsigned short* __restrict__ W1) {
    int idx = blockIdx.x * blockDim.x + threadIdx.x;   // over P*H
    int p = idx >> 10;
    int h = idx & (H_DIM - 1);
    float bre = B[(size_t)idx * 2];
    float bim = B[(size_t)idx * 2 + 1];
    float gre = lam[2 * P_DIM + p];
    float gim = lam[3 * P_DIM + p];
    W1[(size_t)p * H_DIM + h]           = (unsigned short)f2bf_bits(gre * bre - gim * bim);
    W1[(size_t)(P_DIM + p) * H_DIM + h] = (unsigned short)f2bf_bits(gre * bim + gim * bre);
}

// W2[h][k] bf16: k<512 -> 2*C_re[h][k], k>=512 -> -2*C_im   (H x N2)
__global__ void build_W2(const float* __restrict__ C,
                         unsigned short* __restrict__ W2) {
    int idx = blockIdx.x * blockDim.x + threadIdx.x;   // over H*P
    int h = idx >> 9;
    int p = idx & (P_DIM - 1);
    float cre = C[(size_t)idx * 2];
    float cim = C[(size_t)idx * 2 + 1];
    W2[(size_t)h * N2 + p]         = (unsigned short)f2bf_bits( 2.0f * cre);
    W2[(size_t)h * N2 + P_DIM + p] = (unsigned short)f2bf_bits(-2.0f * cim);
}

__global__ void convert_sig(const float* __restrict__ in,
                            unsigned short* __restrict__ out) {
    size_t i = ((size_t)blockIdx.x * 256 + threadIdx.x) * 4;
    float4 v = *(const float4*)(in + i);
    ushort4 o;
    o.x = (unsigned short)f2bf_bits(v.x);
    o.y = (unsigned short)f2bf_bits(v.y);
    o.z = (unsigned short)f2bf_bits(v.z);
    o.w = (unsigned short)f2bf_bits(v.w);
    *(ushort4*)(out + i) = o;
}

// ---------------------------------------------------------------------------
// bf16 MFMA GEMM, m97 structure. Out[m][n] = sum_k A[m][k]*W[n][k]
// A: M x K bf16 row-major. W: N x K bf16 row-major. Tile 128x128, BK=32.
// 256 threads = 4 waves in 2x2; each wave: 4x4 grid of 16x16x32 MFMA.
// MODE 0: store bf16.  MODE 1: store f32 with +D[col]*Sig[row][col].
// ---------------------------------------------------------------------------
template <int MODE>
__global__ __launch_bounds__(256) void gemm_mfma(
    const unsigned short* __restrict__ A,
    const unsigned short* __restrict__ W,
    void* __restrict__ Out, int K,
    const float* __restrict__ Dvec, const float* __restrict__ Sig)
{
    __shared__ unsigned short As[128 * 32];   // [m][k] row-major, 64B rows
    __shared__ unsigned short Ws[128 * 32];   // [n][k]

    const int tid  = threadIdx.x;
    const int lane = tid & 63;
    const int wid  = tid >> 6;
    const int wm   = wid >> 1;     // 0..1
    const int wn   = wid & 1;      // 0..1
    const int m0 = blockIdx.y * 128;
    const int n0 = blockIdx.x * 128;

    // staging: chunk c = i*256 + tid; row = c>>2, k-quarter = c&3 (8 bf16 = 16B)
    const int r0 = tid >> 2;               // 0..63
    const int kq = (tid & 3) * 8;          // element offset in tile row
    const unsigned short* Ag0 = A + (size_t)(m0 + r0) * K + kq;
    const unsigned short* Ag1 = Ag0 + (size_t)64 * K;
    const unsigned short* Wg0 = W + (size_t)(n0 + r0) * K + kq;
    const unsigned short* Wg1 = Wg0 + (size_t)64 * K;
    // LDS dest bases, wave-uniform: chunk base (i*256 + wid*64) * 8 ushorts
    unsigned short* Ad0 = As + (size_t)(wid * 64) * 8;
    unsigned short* Ad1 = As + (size_t)(256 + wid * 64) * 8;
    unsigned short* Wd0 = Ws + (size_t)(wid * 64) * 8;
    unsigned short* Wd1 = Ws + (size_t)(256 + wid * 64) * 8;

    const int fr = lane & 15;   // row-in-16 (A) / col-in-16 (B)
    const int fq = lane >> 4;   // k-quad

    f32x4 acc[4][4] = {};

    for (int k0 = 0; k0 < K; k0 += 32) {
        __syncthreads();                       // prior LDS reads complete
        ASYNC_COPY16(Ag0 + k0, Ad0);
        ASYNC_COPY16(Ag1 + k0, Ad1);
        ASYNC_COPY16(Wg0 + k0, Wd0);
        ASYNC_COPY16(Wg1 + k0, Wd1);
        __syncthreads();                       // vmcnt(0) drained before barrier

        bf16x8 af[4], wf[4];
        #pragma unroll
        for (int mi = 0; mi < 4; ++mi)
            af[mi] = *(const bf16x8*)&As[(size_t)(wm * 64 + mi * 16 + fr) * 32 + fq * 8];
        #pragma unroll
        for (int ni = 0; ni < 4; ++ni)
            wf[ni] = *(const bf16x8*)&Ws[(size_t)(wn * 64 + ni * 16 + fr) * 32 + fq * 8];
        #pragma unroll
        for (int mi = 0; mi < 4; ++mi)
            #pragma unroll
            for (int ni = 0; ni < 4; ++ni)
                acc[mi][ni] = __builtin_amdgcn_mfma_f32_16x16x32_bf16(
                    af[mi], wf[ni], acc[mi][ni], 0, 0, 0);
    }

    // C/D layout (m89-verified): col = lane&15, row = (lane>>4)*4 + reg
    #pragma unroll
    for (int mi = 0; mi < 4; ++mi) {
        #pragma unroll
        for (int ni = 0; ni < 4; ++ni) {
            #pragma unroll
            for (int r = 0; r < 4; ++r) {
                int row = m0 + wm * 64 + mi * 16 + fq * 4 + r;
                int col = n0 + wn * 64 + ni * 16 + fr;
                float v = acc[mi][ni][r];
                if (MODE == 0) {
                    ((unsigned short*)Out)[(size_t)row * 1024 + col] =
                        (unsigned short)f2bf_bits(v);
                } else {
                    v = fmaf(Dvec[col], Sig[(size_t)row * 1024 + col], v);
                    ((float*)Out)[(size_t)row * 1024 + col] = v;
                }
            }
        }
    }
}

// ---------------------------------------------------------------------------
// Scan pass A: per (b, chunk) local scan (zero init) -> chunk-end sums.
// Bu is bf16 packed [l][re|im]; thread t handles p = 2t, 2t+1.
// S layout: [b][c][re(512) | im(512)] fp32.
// ---------------------------------------------------------------------------
__global__ __launch_bounds__(256) void scan_sums(
    const unsigned short* __restrict__ Bu, const float* __restrict__ lam,
    float* __restrict__ S)
{
    int b = blockIdx.x, c = blockIdx.y, t = threadIdx.x;
    int p0 = 2 * t, p1 = 2 * t + 1;
    float lr0 = lam[p0], li0 = lam[P_DIM + p0];
    float lr1 = lam[p1], li1 = lam[P_DIM + p1];
    const unsigned* base =
        (const unsigned*)(Bu + ((size_t)b * L_SEQ + (size_t)c * T_CHUNK) * N2);
    float xr0 = 0, xi0 = 0, xr1 = 0, xi1 = 0;
    for (int j0 = 0; j0 < T_CHUNK; j0 += 8) {
        unsigned R[8], I[8];
        #pragma unroll
        for (int j = 0; j < 8; ++j) {
            R[j] = base[(size_t)(j0 + j) * 512 + t];
            I[j] = base[(size_t)(j0 + j) * 512 + 256 + t];
        }
        #pragma unroll
        for (int j = 0; j < 8; ++j) {
            float nr0 = fmaf(lr0, xr0, fmaf(-li0, xi0, bf_lo(R[j])));
            float ni0 = fmaf(lr0, xi0, fmaf( li0, xr0, bf_lo(I[j])));
            float nr1 = fmaf(lr1, xr1, fmaf(-li1, xi1, bf_hi(R[j])));
            float ni1 = fmaf(lr1, xi1, fmaf( li1, xr1, bf_hi(I[j])));
            xr0 = nr0; xi0 = ni0; xr1 = nr1; xi1 = ni1;
        }
    }
    float* Sb = S + ((size_t)(b * NC + c) * 2) * P_DIM;
    Sb[p0] = xr0; Sb[p1] = xr1;
    Sb[P_DIM + p0] = xi0; Sb[P_DIM + p1] = xi1;
}

// Pass B: carries. cin[b][0]=0; cin[c] = lam^T * cin[c-1] + S[c-1].
__global__ __launch_bounds__(512) void scan_carry(
    const float* __restrict__ S, const float* __restrict__ lam,
    float* __restrict__ CIN)
{
    int b = blockIdx.x, p = threadIdx.x;
    float lr = lam[p], li = lam[P_DIM + p];
    float pr = lr, pi = li;                 // lam^128 via 7 squarings
    #pragma unroll
    for (int i = 0; i < 7; ++i) {
        float nr = pr * pr - pi * pi;
        float ni = 2.0f * pr * pi;
        pr = nr; pi = ni;
    }
    float cr = 0, ci = 0;
    for (int c = 0; c < NC; ++c) {
        float* Cb = CIN + ((size_t)(b * NC + c) * 2) * P_DIM;
        Cb[p] = cr; Cb[P_DIM + p] = ci;
        const float* Sb = S + ((size_t)(b * NC + c) * 2) * P_DIM;
        float sr = Sb[p], si = Sb[P_DIM + p];
        float nr = fmaf(pr, cr, fmaf(-pi, ci, sr));
        float ni = fmaf(pr, ci, fmaf( pi, cr, si));
        cr = nr; ci = ni;
    }
}

// Pass C: x = cin; x = lam*x + u; overwrite Bu with xs (bf16); emit state.
__global__ __launch_bounds__(256) void scan_apply(
    unsigned short* __restrict__ Bu, const float* __restrict__ lam,
    const float* __restrict__ CIN, float* __restrict__ out_state,
    int interleaved)
{
    int b = blockIdx.x, c = blockIdx.y, t = threadIdx.x;
    int p0 = 2 * t, p1 = 2 * t + 1;
    float lr0 = lam[p0], li0 = lam[P_DIM + p0];
    float lr1 = lam[p1], li1 = lam[P_DIM + p1];
    const float* Cb = CIN + ((size_t)(b * NC + c) * 2) * P_DIM;
    float xr0 = Cb[p0], xi0 = Cb[P_DIM + p0];
    float xr1 = Cb[p1], xi1 = Cb[P_DIM + p1];
    unsigned* base =
        (unsigned*)(Bu + ((size_t)b * L_SEQ + (size_t)c * T_CHUNK) * N2);
    for (int j0 = 0; j0 < T_CHUNK; j0 += 8) {
        unsigned R[8], I[8];
        #pragma unroll
        for (int j = 0; j < 8; ++j) {
            R[j] = base[(size_t)(j0 + j) * 512 + t];
            I[j] = base[(size_t)(j0 + j) * 512 + 256 + t];
        }
        #pragma unroll
        for (int j = 0; j < 8; ++j) {
            float nr0 = fmaf(lr0, xr0, fmaf(-li0, xi0, bf_lo(R[j])));
            float ni0 = fmaf(lr0, xi0, fmaf( li0, xr0, bf_lo(I[j])));
            float nr1 = fmaf(lr1, xr1, fmaf(-li1, xi1, bf_hi(R[j])));
            float ni1 = fmaf(lr1, xi1, fmaf( li1, xr1, bf_hi(I[j])));
            xr0 = nr0; xi0 = ni0; xr1 = nr1; xi1 = ni1;
            R[j] = f2bf_bits(nr0) | (f2bf_bits(nr1) << 16);
            I[j] = f2bf_bits(ni0) | (f2bf_bits(ni1) << 16);
        }
        #pragma unroll
        for (int j = 0; j < 8; ++j) {
            base[(size_t)(j0 + j) * 512 + t]       = R[j];
            base[(size_t)(j0 + j) * 512 + 256 + t] = I[j];
        }
    }
    if (c == NC - 1) {
        if (interleaved) {
            out_state[((size_t)b * P_DIM + p0) * 2]     = xr0;
            out_state[((size_t)b * P_DIM + p0) * 2 + 1] = xi0;
            out_state[((size_t)b * P_DIM + p1) * 2]     = xr1;
            out_state[((size_t)b * P_DIM + p1) * 2 + 1] = xi1;
        } else {
            out_state[(size_t)b * P_DIM + p0] = xr0;
            out_state[(size_t)b * P_DIM + p1] = xr1;
        }
    }
}

// ---------------------------------------------------------------------------
extern "C" void kernel_launch(void* const* d_in, const int* in_sizes, int n_in,
                              void* d_out, int out_size, void* d_ws, size_t ws_size,
                              hipStream_t stream)
{
    const float* signal   = (const float*)d_in[0];
    // d_in[1] = prev_state: never reaches the scan's b-component -> no effect
    const float* Lre      = (const float*)d_in[2];
    const float* Lim      = (const float*)d_in[3];
    const float* B        = (const float*)d_in[4];
    const float* C        = (const float*)d_in[5];
    const float* Dv       = (const float*)d_in[6];
    const float* log_step = (const float*)d_in[7];

    // ws layout (bytes)
    char* ws = (char*)d_ws;
    unsigned short* sigbf = (unsigned short*)ws;                      // 32 MB
    unsigned short* Bubf  = (unsigned short*)(ws + 33554432);         // 32 MB
    unsigned short* W1bf  = (unsigned short*)(ws + 67108864);         // 2 MB
    unsigned short* W2bf  = (unsigned short*)(ws + 69206016);         // 2 MB
    float*          lam   = (float*)(ws + 71303168);                  // 8 KB
    float*          S     = (float*)(ws + 71311360);                  // 512 KB
    float*          CIN   = (float*)(ws + 71835648);                  // 512 KB
    size_t need = 72359936;
    if (ws_size < need) return;

    float* y_out = (float*)d_out;
    float* state_out = y_out + (size_t)M_DIM * H_DIM;
    int interleaved = (out_size - M_DIM * H_DIM) >= 2 * BATCH_N * P_DIM;

    setup_lam<<<dim3(2), dim3(256), 0, stream>>>(Lre, Lim, log_step, lam);
    build_W1<<<dim3((P_DIM * H_DIM) / 256), dim3(256), 0, stream>>>(B, lam, W1bf);
    build_W2<<<dim3((H_DIM * P_DIM) / 256), dim3(256), 0, stream>>>(C, W2bf);
    convert_sig<<<dim3((M_DIM * H_DIM) / 1024), dim3(256), 0, stream>>>(signal, sigbf);

    // GEMM1: Bu[m][n] = sum_h sig[m][h] * W1[n][h]   (bf16 out)
    gemm_mfma<0><<<dim3(N2 / 128, M_DIM / 128), dim3(256), 0, stream>>>(
        sigbf, W1bf, Bubf, H_DIM, nullptr, nullptr);

    scan_sums<<<dim3(BATCH_N, NC), dim3(256), 0, stream>>>(Bubf, lam, S);
    scan_carry<<<dim3(BATCH_N), dim3(512), 0, stream>>>(S, lam, CIN);
    scan_apply<<<dim3(BATCH_N, NC), dim3(256), 0, stream>>>(
        Bubf, lam, CIN, state_out, interleaved);

    // GEMM2: y[m][h] = sum_k xs[m][k]*W2[h][k] + D[h]*sig[m][h]  (fp32 out)
    gemm_mfma<1><<<dim3(N2 / 128, M_DIM / 128), dim3(256), 0, stream>>>(
        Bubf, W2bf, y_out, N2, Dv, signal);
}

// Round 4
// 273.018 us; speedup vs baseline: 4.0837x; 1.0662x over previous
//
#include <hip/hip_runtime.h>
#include <math.h>

#define L_SEQ   2048
#define BATCH_N 8
#define H_DIM   1024
#define P_DIM   512
#define M_DIM   (BATCH_N * L_SEQ)   // 16384
#define N2      1024                // packed complex width (re | im)
#define NC      16                  // scan chunks
#define T_CHUNK 128                 // L_SEQ / NC

typedef __attribute__((ext_vector_type(8))) __bf16 bf16x8;
typedef __attribute__((ext_vector_type(4))) float f32x4;

__device__ __forceinline__ unsigned f2bf_bits(float f) {
    unsigned u = __builtin_bit_cast(unsigned, f);
    return (u + 0x7fffu + ((u >> 16) & 1u)) >> 16;   // RNE
}
__device__ __forceinline__ float bf_lo(unsigned v) {
    return __builtin_bit_cast(float, v << 16);
}
__device__ __forceinline__ float bf_hi(unsigned v) {
    return __builtin_bit_cast(float, v & 0xffff0000u);
}
__device__ __forceinline__ float bf2f(unsigned short u) {
    return __builtin_bit_cast(float, (unsigned)u << 16);
}

#define ASYNC_COPY16(gsrc, ldst)                                            \
    __builtin_amdgcn_global_load_lds(                                       \
        (__attribute__((address_space(1))) void*)(gsrc),                    \
        (__attribute__((address_space(3))) void*)(ldst), 16, 0, 0)

// ---------------------------------------------------------------------------
// lam buffer: [lam_re(512) | lam_im(512) | g_re(512) | g_im(512)]  (fp32)
// ---------------------------------------------------------------------------
__global__ void setup_lam(const float* __restrict__ Lre_in,
                          const float* __restrict__ Lim_in,
                          const float* __restrict__ log_step,
                          float* __restrict__ lam) {
    int p = blockIdx.x * blockDim.x + threadIdx.x;
    if (p >= P_DIM) return;
    float step = expf(log_step[p]);
    float c = Lre_in[p];
    float d = Lim_in[p];
    float mag = expf(c * step);
    float ang = d * step;
    float lr = mag * cosf(ang);
    float li = mag * sinf(ang);
    float a = lr - 1.0f, b = li;
    float inv = 1.0f / (c * c + d * d);
    lam[p]             = lr;
    lam[P_DIM + p]     = li;
    lam[2 * P_DIM + p] = (a * c + b * d) * inv;   // g_re
    lam[3 * P_DIM + p] = (b * c - a * d) * inv;   // g_im
}

// Fused weight build.
// W1[n][k] bf16 (N2 x H): n<512 -> B_bar_re, n>=512 -> B_bar_im
// W2[h][k] bf16 (H x N2): k<512 -> 2*C_re,   k>=512 -> -2*C_im
__global__ void build_W(const float* __restrict__ B,
                        const float* __restrict__ C,
                        const float* __restrict__ lam,
                        unsigned short* __restrict__ W1,
                        unsigned short* __restrict__ W2) {
    int idx = blockIdx.x * blockDim.x + threadIdx.x;
    if (idx < P_DIM * H_DIM) {                       // W1 half: idx over P*H
        int p = idx >> 10;
        int h = idx & (H_DIM - 1);
        float bre = B[(size_t)idx * 2];
        float bim = B[(size_t)idx * 2 + 1];
        float gre = lam[2 * P_DIM + p];
        float gim = lam[3 * P_DIM + p];
        W1[(size_t)p * H_DIM + h]           = (unsigned short)f2bf_bits(gre * bre - gim * bim);
        W1[(size_t)(P_DIM + p) * H_DIM + h] = (unsigned short)f2bf_bits(gre * bim + gim * bre);
    } else {                                         // W2 half: idx over H*P
        int j = idx - P_DIM * H_DIM;
        int h = j >> 9;
        int p = j & (P_DIM - 1);
        float cre = C[(size_t)j * 2];
        float cim = C[(size_t)j * 2 + 1];
        W2[(size_t)h * N2 + p]         = (unsigned short)f2bf_bits( 2.0f * cre);
        W2[(size_t)h * N2 + P_DIM + p] = (unsigned short)f2bf_bits(-2.0f * cim);
    }
}

__global__ void convert_sig(const float* __restrict__ in,
                            unsigned short* __restrict__ out) {
    size_t i = ((size_t)blockIdx.x * 256 + threadIdx.x) * 4;
    float4 v = *(const float4*)(in + i);
    ushort4 o;
    o.x = (unsigned short)f2bf_bits(v.x);
    o.y = (unsigned short)f2bf_bits(v.y);
    o.z = (unsigned short)f2bf_bits(v.z);
    o.w = (unsigned short)f2bf_bits(v.w);
    *(ushort4*)(out + i) = o;
}

// ---------------------------------------------------------------------------
// bf16 MFMA GEMM (m97 structure) with XCD-aware swizzle.
// Out[m][n] = sum_k A[m][k]*W[n][k].  A: M x K, W: N x K, both bf16 row-major.
// Tile 128x128, BK=32, 256 thr = 4 waves (2x2), wave = 4x4 of 16x16x32 MFMA.
// 1D grid of 1024 blocks. Block->XCD is round-robin (id%8), so XCD x owns
// m-blocks [16x,16x+16); its 8 n-blocks are consecutive ids -> A-tile is
// fetched once per XCD, W stays L2-resident per XCD.
// MODE 0: bf16 out via LDS-transposed coalesced 16B stores.
// MODE 1: f32 out, + D[col]*bf2f(SigBf[row][col]) fused.
// ---------------------------------------------------------------------------
template <int MODE>
__global__ __launch_bounds__(256) void gemm_mfma(
    const unsigned short* __restrict__ A,
    const unsigned short* __restrict__ W,
    void* __restrict__ Out, int K,
    const float* __restrict__ Dvec, const unsigned short* __restrict__ SigBf)
{
    __shared__ unsigned short smem[128 * 32 * 2];   // As | Ws, 16 KB
    unsigned short* As = smem;
    unsigned short* Ws = smem + 128 * 32;

    const int tid  = threadIdx.x;
    const int lane = tid & 63;
    const int wid  = tid >> 6;
    const int wm   = wid >> 1;     // 0..1
    const int wn   = wid & 1;      // 0..1

    // XCD swizzle: 128 m-blocks x 8 n-blocks
    const int id  = blockIdx.x;
    const int xcd = id & 7;
    const int j   = id >> 3;              // 0..127
    const int mb  = xcd * 16 + (j >> 3);  // m-block
    const int nb  = j & 7;                // n-block
    const int m0 = mb * 128;
    const int n0 = nb * 128;

    // staging: chunk c = i*256 + tid; row = c>>2, k-octet = c&3 (8 bf16 = 16B)
    const int r0 = tid >> 2;
    const int kq = (tid & 3) * 8;
    const unsigned short* Ag0 = A + (size_t)(m0 + r0) * K + kq;
    const unsigned short* Ag1 = Ag0 + (size_t)64 * K;
    const unsigned short* Wg0 = W + (size_t)(n0 + r0) * K + kq;
    const unsigned short* Wg1 = Wg0 + (size_t)64 * K;
    unsigned short* Ad0 = As + (size_t)(wid * 64) * 8;
    unsigned short* Ad1 = As + (size_t)(256 + wid * 64) * 8;
    unsigned short* Wd0 = Ws + (size_t)(wid * 64) * 8;
    unsigned short* Wd1 = Ws + (size_t)(256 + wid * 64) * 8;

    const int fr = lane & 15;   // row-in-16 (A) / col-in-16 (B)
    const int fq = lane >> 4;   // k-quad

    f32x4 acc[4][4] = {};

    for (int k0 = 0; k0 < K; k0 += 32) {
        __syncthreads();
        ASYNC_COPY16(Ag0 + k0, Ad0);
        ASYNC_COPY16(Ag1 + k0, Ad1);
        ASYNC_COPY16(Wg0 + k0, Wd0);
        ASYNC_COPY16(Wg1 + k0, Wd1);
        __syncthreads();

        bf16x8 af[4], wf[4];
        #pragma unroll
        for (int mi = 0; mi < 4; ++mi)
            af[mi] = *(const bf16x8*)&As[(size_t)(wm * 64 + mi * 16 + fr) * 32 + fq * 8];
        #pragma unroll
        for (int ni = 0; ni < 4; ++ni)
            wf[ni] = *(const bf16x8*)&Ws[(size_t)(wn * 64 + ni * 16 + fr) * 32 + fq * 8];
        #pragma unroll
        for (int mi = 0; mi < 4; ++mi)
            #pragma unroll
            for (int ni = 0; ni < 4; ++ni)
                acc[mi][ni] = __builtin_amdgcn_mfma_f32_16x16x32_bf16(
                    af[mi], wf[ni], acc[mi][ni], 0, 0, 0);
    }

    // C/D layout (m89): col = lane&15, row = (lane>>4)*4 + reg
    if (MODE == 0) {
        // bf16 out: transpose through LDS (two 64x128 half-tiles, 16 KB each)
        unsigned short* T = smem;
        #pragma unroll
        for (int h = 0; h < 2; ++h) {
            __syncthreads();       // prior LDS readers done
            if (wm == h) {
                #pragma unroll
                for (int mi = 0; mi < 4; ++mi)
                    #pragma unroll
                    for (int ni = 0; ni < 4; ++ni)
                        #pragma unroll
                        for (int r = 0; r < 4; ++r) {
                            int lrow = mi * 16 + fq * 4 + r;      // 0..63
                            int lcol = wn * 64 + ni * 16 + fr;    // 0..127
                            T[lrow * 128 + lcol] =
                                (unsigned short)f2bf_bits(acc[mi][ni][r]);
                        }
            }
            __syncthreads();
            // 64 rows x 128 cols = 8192 ushorts = 1024 chunks of 8 (16B).
            // Each row = 16 chunks -> row = chunk>>4, col offset = (chunk&15)*8.
            #pragma unroll
            for (int jj = 0; jj < 4; ++jj) {
                int chunk = jj * 256 + tid;        // 0..1023
                int row = chunk >> 4;              // 0..63
                int co  = (chunk & 15) * 8;        // 0..120
                *(ulonglong2*)((unsigned short*)Out +
                    (size_t)(m0 + h * 64 + row) * 1024 + n0 + co) =
                    *(const ulonglong2*)&T[row * 128 + co];
            }
        }
    } else {
        #pragma unroll
        for (int mi = 0; mi < 4; ++mi) {
            #pragma unroll
            for (int ni = 0; ni < 4; ++ni) {
                #pragma unroll
                for (int r = 0; r < 4; ++r) {
                    int row = m0 + wm * 64 + mi * 16 + fq * 4 + r;
                    int col = n0 + wn * 64 + ni * 16 + fr;
                    float v = acc[mi][ni][r];
                    v = fmaf(Dvec[col], bf2f(SigBf[(size_t)row * 1024 + col]), v);
                    ((float*)Out)[(size_t)row * 1024 + col] = v;
                }
            }
        }
    }
}

// ---------------------------------------------------------------------------
// Scan pass A: per (b, chunk) local scan (zero init) -> chunk-end sums.
// ---------------------------------------------------------------------------
__global__ __launch_bounds__(256) void scan_sums(
    const unsigned short* __restrict__ Bu, const float* __restrict__ lam,
    float* __restrict__ S)
{
    int b = blockIdx.x, c = blockIdx.y, t = threadIdx.x;
    int p0 = 2 * t, p1 = 2 * t + 1;
    float lr0 = lam[p0], li0 = lam[P_DIM + p0];
    float lr1 = lam[p1], li1 = lam[P_DIM + p1];
    const unsigned* base =
        (const unsigned*)(Bu + ((size_t)b * L_SEQ + (size_t)c * T_CHUNK) * N2);
    float xr0 = 0, xi0 = 0, xr1 = 0, xi1 = 0;
    for (int j0 = 0; j0 < T_CHUNK; j0 += 8) {
        unsigned R[8], I[8];
        #pragma unroll
        for (int j = 0; j < 8; ++j) {
            R[j] = base[(size_t)(j0 + j) * 512 + t];
            I[j] = base[(size_t)(j0 + j) * 512 + 256 + t];
        }
        #pragma unroll
        for (int j = 0; j < 8; ++j) {
            float nr0 = fmaf(lr0, xr0, fmaf(-li0, xi0, bf_lo(R[j])));
            float ni0 = fmaf(lr0, xi0, fmaf( li0, xr0, bf_lo(I[j])));
            float nr1 = fmaf(lr1, xr1, fmaf(-li1, xi1, bf_hi(R[j])));
            float ni1 = fmaf(lr1, xi1, fmaf( li1, xr1, bf_hi(I[j])));
            xr0 = nr0; xi0 = ni0; xr1 = nr1; xi1 = ni1;
        }
    }
    float* Sb = S + ((size_t)(b * NC + c) * 2) * P_DIM;
    Sb[p0] = xr0; Sb[p1] = xr1;
    Sb[P_DIM + p0] = xi0; Sb[P_DIM + p1] = xi1;
}

// Pass B: carries. cin[b][0]=0; cin[c] = lam^T * cin[c-1] + S[c-1].
__global__ __launch_bounds__(512) void scan_carry(
    const float* __restrict__ S, const float* __restrict__ lam,
    float* __restrict__ CIN)
{
    int b = blockIdx.x, p = threadIdx.x;
    float lr = lam[p], li = lam[P_DIM + p];
    float pr = lr, pi = li;                 // lam^128 via 7 squarings
    #pragma unroll
    for (int i = 0; i < 7; ++i) {
        float nr = pr * pr - pi * pi;
        float ni = 2.0f * pr * pi;
        pr = nr; pi = ni;
    }
    float cr = 0, ci = 0;
    for (int c = 0; c < NC; ++c) {
        float* Cb = CIN + ((size_t)(b * NC + c) * 2) * P_DIM;
        Cb[p] = cr; Cb[P_DIM + p] = ci;
        const float* Sb = S + ((size_t)(b * NC + c) * 2) * P_DIM;
        float sr = Sb[p], si = Sb[P_DIM + p];
        float nr = fmaf(pr, cr, fmaf(-pi, ci, sr));
        float ni = fmaf(pr, ci, fmaf( pi, cr, si));
        cr = nr; ci = ni;
    }
}

// Pass C: x = cin; x = lam*x + u; overwrite Bu with xs (bf16); emit state.
__global__ __launch_bounds__(256) void scan_apply(
    unsigned short* __restrict__ Bu, const float* __restrict__ lam,
    const float* __restrict__ CIN, float* __restrict__ out_state,
    int interleaved)
{
    int b = blockIdx.x, c = blockIdx.y, t = threadIdx.x;
    int p0 = 2 * t, p1 = 2 * t + 1;
    float lr0 = lam[p0], li0 = lam[P_DIM + p0];
    float lr1 = lam[p1], li1 = lam[P_DIM + p1];
    const float* Cb = CIN + ((size_t)(b * NC + c) * 2) * P_DIM;
    float xr0 = Cb[p0], xi0 = Cb[P_DIM + p0];
    float xr1 = Cb[p1], xi1 = Cb[P_DIM + p1];
    unsigned* base =
        (unsigned*)(Bu + ((size_t)b * L_SEQ + (size_t)c * T_CHUNK) * N2);
    for (int j0 = 0; j0 < T_CHUNK; j0 += 8) {
        unsigned R[8], I[8];
        #pragma unroll
        for (int j = 0; j < 8; ++j) {
            R[j] = base[(size_t)(j0 + j) * 512 + t];
            I[j] = base[(size_t)(j0 + j) * 512 + 256 + t];
        }
        #pragma unroll
        for (int j = 0; j < 8; ++j) {
            float nr0 = fmaf(lr0, xr0, fmaf(-li0, xi0, bf_lo(R[j])));
            float ni0 = fmaf(lr0, xi0, fmaf( li0, xr0, bf_lo(I[j])));
            float nr1 = fmaf(lr1, xr1, fmaf(-li1, xi1, bf_hi(R[j])));
            float ni1 = fmaf(lr1, xi1, fmaf( li1, xr1, bf_hi(I[j])));
            xr0 = nr0; xi0 = ni0; xr1 = nr1; xi1 = ni1;
            R[j] = f2bf_bits(nr0) | (f2bf_bits(nr1) << 16);
            I[j] = f2bf_bits(ni0) | (f2bf_bits(ni1) << 16);
        }
        #pragma unroll
        for (int j = 0; j < 8; ++j) {
            base[(size_t)(j0 + j) * 512 + t]       = R[j];
            base[(size_t)(j0 + j) * 512 + 256 + t] = I[j];
        }
    }
    if (c == NC - 1) {
        if (interleaved) {
            out_state[((size_t)b * P_DIM + p0) * 2]     = xr0;
            out_state[((size_t)b * P_DIM + p0) * 2 + 1] = xi0;
            out_state[((size_t)b * P_DIM + p1) * 2]     = xr1;
            out_state[((size_t)b * P_DIM + p1) * 2 + 1] = xi1;
        } else {
            out_state[(size_t)b * P_DIM + p0] = xr0;
            out_state[(size_t)b * P_DIM + p1] = xr1;
        }
    }
}

// ---------------------------------------------------------------------------
extern "C" void kernel_launch(void* const* d_in, const int* in_sizes, int n_in,
                              void* d_out, int out_size, void* d_ws, size_t ws_size,
                              hipStream_t stream)
{
    const float* signal   = (const float*)d_in[0];
    // d_in[1] = prev_state: never reaches the scan's b-component -> no effect
    const float* Lre      = (const float*)d_in[2];
    const float* Lim      = (const float*)d_in[3];
    const float* B        = (const float*)d_in[4];
    const float* C        = (const float*)d_in[5];
    const float* Dv       = (const float*)d_in[6];
    const float* log_step = (const float*)d_in[7];

    // ws layout (bytes)
    char* ws = (char*)d_ws;
    unsigned short* sigbf = (unsigned short*)ws;                      // 32 MB
    unsigned short* Bubf  = (unsigned short*)(ws + 33554432);         // 32 MB
    unsigned short* W1bf  = (unsigned short*)(ws + 67108864);         // 2 MB
    unsigned short* W2bf  = (unsigned short*)(ws + 69206016);         // 2 MB
    float*          lam   = (float*)(ws + 71303168);                  // 8 KB
    float*          S     = (float*)(ws + 71311360);                  // 512 KB
    float*          CIN   = (float*)(ws + 71835648);                  // 512 KB
    size_t need = 72359936;
    if (ws_size < need) return;

    float* y_out = (float*)d_out;
    float* state_out = y_out + (size_t)M_DIM * H_DIM;
    int interleaved = (out_size - M_DIM * H_DIM) >= 2 * BATCH_N * P_DIM;

    setup_lam<<<dim3(2), dim3(256), 0, stream>>>(Lre, Lim, log_step, lam);
    build_W<<<dim3((2 * P_DIM * H_DIM) / 256), dim3(256), 0, stream>>>(
        B, C, lam, W1bf, W2bf);
    convert_sig<<<dim3((M_DIM * H_DIM) / 1024), dim3(256), 0, stream>>>(signal, sigbf);

    // GEMM1: Bu[m][n] = sum_h sig[m][h] * W1[n][h]   (bf16 out)
    gemm_mfma<0><<<dim3(1024), dim3(256), 0, stream>>>(
        sigbf, W1bf, Bubf, H_DIM, nullptr, nullptr);

    scan_sums<<<dim3(BATCH_N, NC), dim3(256), 0, stream>>>(Bubf, lam, S);
    scan_carry<<<dim3(BATCH_N), dim3(512), 0, stream>>>(S, lam, CIN);
    scan_apply<<<dim3(BATCH_N, NC), dim3(256), 0, stream>>>(
        Bubf, lam, CIN, state_out, interleaved);

    // GEMM2: y[m][h] = sum_k xs[m][k]*W2[h][k] + D[h]*sig[m][h]  (fp32 out)
    gemm_mfma<1><<<dim3(1024), dim3(256), 0, stream>>>(
        Bubf, W2bf, y_out, N2, Dv, sigbf);
}

// Round 5
// 234.198 us; speedup vs baseline: 4.7606x; 1.1658x over previous
//
#include <hip/hip_runtime.h>
#include <math.h>

#define L_SEQ   2048
#define BATCH_N 8
#define H_DIM   1024
#define P_DIM   512
#define M_DIM   (BATCH_N * L_SEQ)   // 16384
#define N2      1024                // packed complex width (re | im)
#define NC      32                  // scan chunks
#define T_CHUNK 64                  // L_SEQ / NC

typedef __attribute__((ext_vector_type(8))) __bf16 bf16x8;
typedef __attribute__((ext_vector_type(4))) float f32x4;

__device__ __forceinline__ unsigned f2bf_bits(float f) {
    unsigned u = __builtin_bit_cast(unsigned, f);
    return (u + 0x7fffu + ((u >> 16) & 1u)) >> 16;   // RNE
}
__device__ __forceinline__ float bf_lo(unsigned v) {
    return __builtin_bit_cast(float, v << 16);
}
__device__ __forceinline__ float bf_hi(unsigned v) {
    return __builtin_bit_cast(float, v & 0xffff0000u);
}
__device__ __forceinline__ float bf2f(unsigned short u) {
    return __builtin_bit_cast(float, (unsigned)u << 16);
}

#define ASYNC_COPY16(gsrc, ldst)                                            \
    __builtin_amdgcn_global_load_lds(                                       \
        (__attribute__((address_space(1))) void*)(gsrc),                    \
        (__attribute__((address_space(3))) void*)(ldst), 16, 0, 0)

// ---------------------------------------------------------------------------
// lam buffer: [lam_re(512) | lam_im(512) | g_re(512) | g_im(512)]  (fp32)
// ---------------------------------------------------------------------------
__global__ void setup_lam(const float* __restrict__ Lre_in,
                          const float* __restrict__ Lim_in,
                          const float* __restrict__ log_step,
                          float* __restrict__ lam) {
    int p = blockIdx.x * blockDim.x + threadIdx.x;
    if (p >= P_DIM) return;
    float step = expf(log_step[p]);
    float c = Lre_in[p];
    float d = Lim_in[p];
    float mag = expf(c * step);
    float ang = d * step;
    float lr = mag * cosf(ang);
    float li = mag * sinf(ang);
    float a = lr - 1.0f, b = li;
    float inv = 1.0f / (c * c + d * d);
    lam[p]             = lr;
    lam[P_DIM + p]     = li;
    lam[2 * P_DIM + p] = (a * c + b * d) * inv;   // g_re
    lam[3 * P_DIM + p] = (b * c - a * d) * inv;   // g_im
}

// Fused weight build.
// W1[n][k] bf16 (N2 x H): n<512 -> B_bar_re, n>=512 -> B_bar_im
// W2[h][k] bf16 (H x N2): k<512 -> 2*C_re,   k>=512 -> -2*C_im
__global__ void build_W(const float* __restrict__ B,
                        const float* __restrict__ C,
                        const float* __restrict__ lam,
                        unsigned short* __restrict__ W1,
                        unsigned short* __restrict__ W2) {
    int idx = blockIdx.x * blockDim.x + threadIdx.x;
    if (idx < P_DIM * H_DIM) {                       // W1 half: idx over P*H
        int p = idx >> 10;
        int h = idx & (H_DIM - 1);
        float bre = B[(size_t)idx * 2];
        float bim = B[(size_t)idx * 2 + 1];
        float gre = lam[2 * P_DIM + p];
        float gim = lam[3 * P_DIM + p];
        W1[(size_t)p * H_DIM + h]           = (unsigned short)f2bf_bits(gre * bre - gim * bim);
        W1[(size_t)(P_DIM + p) * H_DIM + h] = (unsigned short)f2bf_bits(gre * bim + gim * bre);
    } else {                                         // W2 half: idx over H*P
        int j = idx - P_DIM * H_DIM;
        int h = j >> 9;
        int p = j & (P_DIM - 1);
        float cre = C[(size_t)j * 2];
        float cim = C[(size_t)j * 2 + 1];
        W2[(size_t)h * N2 + p]         = (unsigned short)f2bf_bits( 2.0f * cre);
        W2[(size_t)h * N2 + P_DIM + p] = (unsigned short)f2bf_bits(-2.0f * cim);
    }
}

__global__ void convert_sig(const float* __restrict__ in,
                            unsigned short* __restrict__ out) {
    size_t i = ((size_t)blockIdx.x * 256 + threadIdx.x) * 4;
    float4 v = *(const float4*)(in + i);
    ushort4 o;
    o.x = (unsigned short)f2bf_bits(v.x);
    o.y = (unsigned short)f2bf_bits(v.y);
    o.z = (unsigned short)f2bf_bits(v.z);
    o.w = (unsigned short)f2bf_bits(v.w);
    *(ushort4*)(out + i) = o;
}

// ---------------------------------------------------------------------------
// bf16 MFMA GEMM. Out[m][n] = sum_k A[m][k]*W[n][k].
// A: M x K bf16 row-major, W: N x K bf16 row-major (K = 1024).
// Block tile 256(m) x 128(n), BK=64. 256 thr = 4 waves stacked in m;
// wave tile 64 x 128 = 4 x 8 frags of 16x16x32 MFMA (12 LDS b128 reads
// per 32 MFMA -> 1.33x less LDS BW than 4x4).
// LDS k-slot swizzle: slot' = (slot + (row>>1)) & 7 -- implemented by
// rotating the *global* source quad per lane at stage time (stays inside
// the row's 128 B segment -> coalescing preserved; global_load_lds's
// wave-uniform-dest constraint respected). Fragment reads then touch each
// bank exactly 2x (free; was 8-way conflict).
// Grid: 512 blocks, XCD-swizzled: XCD x owns m-blocks [8x, 8x+8).
// MODE 0: bf16 out via LDS-transposed coalesced 16B stores (2 phases).
// MODE 1: f32 out, + D[col]*bf2f(SigBf[row][col]) fused.
// ---------------------------------------------------------------------------
template <int MODE>
__global__ __launch_bounds__(256, 2) void gemm_mfma(
    const unsigned short* __restrict__ A,
    const unsigned short* __restrict__ W,
    void* __restrict__ Out, int K,
    const float* __restrict__ Dvec, const unsigned short* __restrict__ SigBf)
{
    __shared__ unsigned short smem[256 * 64 + 128 * 64];   // As 32K | Ws 16K
    unsigned short* As = smem;
    unsigned short* Ws = smem + 256 * 64;

    const int tid  = threadIdx.x;
    const int lane = tid & 63;
    const int wid  = tid >> 6;     // wave id = m-stripe 0..3
    const int wm   = wid;

    // XCD swizzle: 64 m-blocks x 8 n-blocks, XCD x -> m-blocks [8x, 8x+8)
    const int id  = blockIdx.x;
    const int xcd = id & 7;
    const int j   = id >> 3;              // 0..63
    const int mb  = xcd * 8 + (j >> 3);   // m-block (256 rows)
    const int nb  = j & 7;                // n-block (128 cols)
    const int m0 = mb * 256;
    const int n0 = nb * 128;

    // --- staging geometry -------------------------------------------------
    // chunk c (16 B): row = c>>3, slot = c&7. Swizzle: slot holds global
    // quad qg = (slot - (row>>1)) & 7.  For c = i*256 + tid:
    //   row = i*32 + (tid>>3)  ->  (row>>1)&7 = (tid>>4)&7   (i*16 % 8 == 0)
    const int srow = tid >> 3;                                  // 0..31
    const int qg   = ((tid & 7) - ((tid >> 4) & 7)) & 7;        // const/lane
    const unsigned short* Abase = A + (size_t)(m0 + srow) * K + qg * 8;
    const unsigned short* Wbase = W + (size_t)(n0 + srow) * K + qg * 8;

    const int fr = lane & 15;        // m-row / n-col within 16
    const int fq = (lane >> 4) & 3;  // k-quad within 32
    const int sw = fr >> 1;          // swizzle rotation for this lane

    f32x4 acc[4][8] = {};

    for (int k0 = 0; k0 < K; k0 += 64) {
        __syncthreads();
        #pragma unroll
        for (int i = 0; i < 8; ++i)      // A: 2048 chunks
            ASYNC_COPY16(Abase + (size_t)(i * 32) * K + k0,
                         As + (size_t)(i * 256 + wid * 64) * 8);
        #pragma unroll
        for (int i = 0; i < 4; ++i)      // W: 1024 chunks
            ASYNC_COPY16(Wbase + (size_t)(i * 32) * K + k0,
                         Ws + (size_t)(i * 256 + wid * 64) * 8);
        __syncthreads();

        #pragma unroll
        for (int kk = 0; kk < 2; ++kk) {
            bf16x8 af[4], wf[8];
            #pragma unroll
            for (int mi = 0; mi < 4; ++mi) {
                int row = wm * 64 + mi * 16 + fr;
                int sl  = (kk * 4 + fq + sw) & 7;
                af[mi] = *(const bf16x8*)&As[(size_t)row * 64 + sl * 8];
            }
            #pragma unroll
            for (int ni = 0; ni < 8; ++ni) {
                int row = ni * 16 + fr;
                int sl  = (kk * 4 + fq + sw) & 7;
                wf[ni] = *(const bf16x8*)&Ws[(size_t)row * 64 + sl * 8];
            }
            #pragma unroll
            for (int mi = 0; mi < 4; ++mi)
                #pragma unroll
                for (int ni = 0; ni < 8; ++ni)
                    acc[mi][ni] = __builtin_amdgcn_mfma_f32_16x16x32_bf16(
                        af[mi], wf[ni], acc[mi][ni], 0, 0, 0);
        }
    }

    // C/D layout (m89): col = lane&15, row = (lane>>4)*4 + reg
    if (MODE == 0) {
        // Transpose through LDS, 2 phases of 2 waves (32 KB region).
        unsigned short* T = smem;
        #pragma unroll
        for (int h = 0; h < 2; ++h) {
            __syncthreads();
            if ((wm >> 1) == h) {
                unsigned short* Tw = T + (wm & 1) * 8192;
                #pragma unroll
                for (int mi = 0; mi < 4; ++mi)
                    #pragma unroll
                    for (int ni = 0; ni < 8; ++ni)
                        #pragma unroll
                        for (int r = 0; r < 4; ++r) {
                            int lrow = mi * 16 + fq * 4 + r;      // 0..63
                            int lcol = ni * 16 + fr;              // 0..127
                            Tw[lrow * 128 + lcol] =
                                (unsigned short)f2bf_bits(acc[mi][ni][r]);
                        }
            }
            __syncthreads();
            // 128 rows x 128 cols = 2048 chunks of 8 ushorts (16 B)
            #pragma unroll
            for (int jj = 0; jj < 8; ++jj) {
                int chunk = jj * 256 + tid;        // 0..2047
                int grow  = chunk >> 4;            // 0..127
                int co    = (chunk & 15) * 8;      // 0..120
                *(ulonglong2*)((unsigned short*)Out +
                    (size_t)(m0 + h * 128 + grow) * 1024 + n0 + co) =
                    *(const ulonglong2*)&T[grow * 128 + co];
            }
        }
    } else {
        float Dl[8];
        #pragma unroll
        for (int ni = 0; ni < 8; ++ni)
            Dl[ni] = Dvec[n0 + ni * 16 + fr];
        #pragma unroll
        for (int mi = 0; mi < 4; ++mi) {
            #pragma unroll
            for (int ni = 0; ni < 8; ++ni) {
                #pragma unroll
                for (int r = 0; r < 4; ++r) {
                    int row = m0 + wm * 64 + mi * 16 + fq * 4 + r;
                    int col = n0 + ni * 16 + fr;
                    float v = acc[mi][ni][r];
                    v = fmaf(Dl[ni], bf2f(SigBf[(size_t)row * 1024 + col]), v);
                    ((float*)Out)[(size_t)row * 1024 + col] = v;
                }
            }
        }
    }
}

// ---------------------------------------------------------------------------
// Scan pass A: per (b, chunk) local scan (zero init) -> chunk-end sums.
// ---------------------------------------------------------------------------
__global__ __launch_bounds__(256) void scan_sums(
    const unsigned short* __restrict__ Bu, const float* __restrict__ lam,
    float* __restrict__ S)
{
    int b = blockIdx.x, c = blockIdx.y, t = threadIdx.x;
    int p0 = 2 * t, p1 = 2 * t + 1;
    float lr0 = lam[p0], li0 = lam[P_DIM + p0];
    float lr1 = lam[p1], li1 = lam[P_DIM + p1];
    const unsigned* base =
        (const unsigned*)(Bu + ((size_t)b * L_SEQ + (size_t)c * T_CHUNK) * N2);
    float xr0 = 0, xi0 = 0, xr1 = 0, xi1 = 0;
    for (int j0 = 0; j0 < T_CHUNK; j0 += 8) {
        unsigned R[8], I[8];
        #pragma unroll
        for (int j = 0; j < 8; ++j) {
            R[j] = base[(size_t)(j0 + j) * 512 + t];
            I[j] = base[(size_t)(j0 + j) * 512 + 256 + t];
        }
        #pragma unroll
        for (int j = 0; j < 8; ++j) {
            float nr0 = fmaf(lr0, xr0, fmaf(-li0, xi0, bf_lo(R[j])));
            float ni0 = fmaf(lr0, xi0, fmaf( li0, xr0, bf_lo(I[j])));
            float nr1 = fmaf(lr1, xr1, fmaf(-li1, xi1, bf_hi(R[j])));
            float ni1 = fmaf(lr1, xi1, fmaf( li1, xr1, bf_hi(I[j])));
            xr0 = nr0; xi0 = ni0; xr1 = nr1; xi1 = ni1;
        }
    }
    float* Sb = S + ((size_t)(b * NC + c) * 2) * P_DIM;
    Sb[p0] = xr0; Sb[p1] = xr1;
    Sb[P_DIM + p0] = xi0; Sb[P_DIM + p1] = xi1;
}

// Pass B: carries. cin[b][0]=0; cin[c] = lam^T_CHUNK * cin[c-1] + S[c-1].
__global__ __launch_bounds__(512) void scan_carry(
    const float* __restrict__ S, const float* __restrict__ lam,
    float* __restrict__ CIN)
{
    int b = blockIdx.x, p = threadIdx.x;
    float lr = lam[p], li = lam[P_DIM + p];
    float pr = lr, pi = li;                 // lam^64 via 6 squarings
    #pragma unroll
    for (int i = 0; i < 6; ++i) {
        float nr = pr * pr - pi * pi;
        float ni = 2.0f * pr * pi;
        pr = nr; pi = ni;
    }
    float cr = 0, ci = 0;
    for (int c = 0; c < NC; ++c) {
        float* Cb = CIN + ((size_t)(b * NC + c) * 2) * P_DIM;
        Cb[p] = cr; Cb[P_DIM + p] = ci;
        const float* Sb = S + ((size_t)(b * NC + c) * 2) * P_DIM;
        float sr = Sb[p], si = Sb[P_DIM + p];
        float nr = fmaf(pr, cr, fmaf(-pi, ci, sr));
        float ni = fmaf(pr, ci, fmaf( pi, cr, si));
        cr = nr; ci = ni;
    }
}

// Pass C: x = cin; x = lam*x + u; overwrite Bu with xs (bf16); emit state.
__global__ __launch_bounds__(256) void scan_apply(
    unsigned short* __restrict__ Bu, const float* __restrict__ lam,
    const float* __restrict__ CIN, float* __restrict__ out_state,
    int interleaved)
{
    int b = blockIdx.x, c = blockIdx.y, t = threadIdx.x;
    int p0 = 2 * t, p1 = 2 * t + 1;
    float lr0 = lam[p0], li0 = lam[P_DIM + p0];
    float lr1 = lam[p1], li1 = lam[P_DIM + p1];
    const float* Cb = CIN + ((size_t)(b * NC + c) * 2) * P_DIM;
    float xr0 = Cb[p0], xi0 = Cb[P_DIM + p0];
    float xr1 = Cb[p1], xi1 = Cb[P_DIM + p1];
    unsigned* base =
        (unsigned*)(Bu + ((size_t)b * L_SEQ + (size_t)c * T_CHUNK) * N2);
    for (int j0 = 0; j0 < T_CHUNK; j0 += 8) {
        unsigned R[8], I[8];
        #pragma unroll
        for (int j = 0; j < 8; ++j) {
            R[j] = base[(size_t)(j0 + j) * 512 + t];
            I[j] = base[(size_t)(j0 + j) * 512 + 256 + t];
        }
        #pragma unroll
        for (int j = 0; j < 8; ++j) {
            float nr0 = fmaf(lr0, xr0, fmaf(-li0, xi0, bf_lo(R[j])));
            float ni0 = fmaf(lr0, xi0, fmaf( li0, xr0, bf_lo(I[j])));
            float nr1 = fmaf(lr1, xr1, fmaf(-li1, xi1, bf_hi(R[j])));
            float ni1 = fmaf(lr1, xi1, fmaf( li1, xr1, bf_hi(I[j])));
            xr0 = nr0; xi0 = ni0; xr1 = nr1; xi1 = ni1;
            R[j] = f2bf_bits(nr0) | (f2bf_bits(nr1) << 16);
            I[j] = f2bf_bits(ni0) | (f2bf_bits(ni1) << 16);
        }
        #pragma unroll
        for (int j = 0; j < 8; ++j) {
            base[(size_t)(j0 + j) * 512 + t]       = R[j];
            base[(size_t)(j0 + j) * 512 + 256 + t] = I[j];
        }
    }
    if (c == NC - 1) {
        if (interleaved) {
            out_state[((size_t)b * P_DIM + p0) * 2]     = xr0;
            out_state[((size_t)b * P_DIM + p0) * 2 + 1] = xi0;
            out_state[((size_t)b * P_DIM + p1) * 2]     = xr1;
            out_state[((size_t)b * P_DIM + p1) * 2 + 1] = xi1;
        } else {
            out_state[(size_t)b * P_DIM + p0] = xr0;
            out_state[(size_t)b * P_DIM + p1] = xr1;
        }
    }
}

// ---------------------------------------------------------------------------
extern "C" void kernel_launch(void* const* d_in, const int* in_sizes, int n_in,
                              void* d_out, int out_size, void* d_ws, size_t ws_size,
                              hipStream_t stream)
{
    const float* signal   = (const float*)d_in[0];
    // d_in[1] = prev_state: never reaches the scan's b-component -> no effect
    const float* Lre      = (const float*)d_in[2];
    const float* Lim      = (const float*)d_in[3];
    const float* B        = (const float*)d_in[4];
    const float* C        = (const float*)d_in[5];
    const float* Dv       = (const float*)d_in[6];
    const float* log_step = (const float*)d_in[7];

    // ws layout (bytes)
    char* ws = (char*)d_ws;
    unsigned short* sigbf = (unsigned short*)ws;                      // 32 MB
    unsigned short* Bubf  = (unsigned short*)(ws + 33554432);         // 32 MB
    unsigned short* W1bf  = (unsigned short*)(ws + 67108864);         // 2 MB
    unsigned short* W2bf  = (unsigned short*)(ws + 69206016);         // 2 MB
    float*          lam   = (float*)(ws + 71303168);                  // 8 KB
    float*          S     = (float*)(ws + 71311360);                  // 512 KB
    float*          CIN   = (float*)(ws + 71835648);                  // 512 KB
    size_t need = 72359936;
    if (ws_size < need) return;

    float* y_out = (float*)d_out;
    float* state_out = y_out + (size_t)M_DIM * H_DIM;
    int interleaved = (out_size - M_DIM * H_DIM) >= 2 * BATCH_N * P_DIM;

    setup_lam<<<dim3(2), dim3(256), 0, stream>>>(Lre, Lim, log_step, lam);
    build_W<<<dim3((2 * P_DIM * H_DIM) / 256), dim3(256), 0, stream>>>(
        B, C, lam, W1bf, W2bf);
    convert_sig<<<dim3((M_DIM * H_DIM) / 1024), dim3(256), 0, stream>>>(signal, sigbf);

    // GEMM1: Bu[m][n] = sum_h sig[m][h] * W1[n][h]   (bf16 out)
    gemm_mfma<0><<<dim3(512), dim3(256), 0, stream>>>(
        sigbf, W1bf, Bubf, H_DIM, nullptr, nullptr);

    scan_sums<<<dim3(BATCH_N, NC), dim3(256), 0, stream>>>(Bubf, lam, S);
    scan_carry<<<dim3(BATCH_N), dim3(512), 0, stream>>>(S, lam, CIN);
    scan_apply<<<dim3(BATCH_N, NC), dim3(256), 0, stream>>>(
        Bubf, lam, CIN, state_out, interleaved);

    // GEMM2: y[m][h] = sum_k xs[m][k]*W2[h][k] + D[h]*sig[m][h]  (fp32 out)
    gemm_mfma<1><<<dim3(512), dim3(256), 0, stream>>>(
        Bubf, W2bf, y_out, N2, Dv, sigbf);
}

// Round 6
// 231.006 us; speedup vs baseline: 4.8263x; 1.0138x over previous
//
#include <hip/hip_runtime.h>
#include <math.h>

#define L_SEQ   2048
#define BATCH_N 8
#define H_DIM   1024
#define P_DIM   512
#define M_DIM   (BATCH_N * L_SEQ)   // 16384
#define N2      1024                // packed complex width (re | im)
#define NC      32                  // scan chunks
#define T_CHUNK 64                  // L_SEQ / NC

typedef __attribute__((ext_vector_type(8))) __bf16 bf16x8;
typedef __attribute__((ext_vector_type(4))) float f32x4;

__device__ __forceinline__ unsigned f2bf_bits(float f) {
    unsigned u = __builtin_bit_cast(unsigned, f);
    return (u + 0x7fffu + ((u >> 16) & 1u)) >> 16;   // RNE
}
__device__ __forceinline__ float bf_lo(unsigned v) {
    return __builtin_bit_cast(float, v << 16);
}
__device__ __forceinline__ float bf_hi(unsigned v) {
    return __builtin_bit_cast(float, v & 0xffff0000u);
}
__device__ __forceinline__ float bf2f(unsigned short u) {
    return __builtin_bit_cast(float, (unsigned)u << 16);
}

#define ASYNC_COPY16(gsrc, ldst)                                            \
    __builtin_amdgcn_global_load_lds(                                       \
        (__attribute__((address_space(1))) void*)(gsrc),                    \
        (__attribute__((address_space(3))) void*)(ldst), 16, 0, 0)

// ---------------------------------------------------------------------------
// lam buffer: [lam_re(512) | lam_im(512) | g_re(512) | g_im(512)]  (fp32)
// ---------------------------------------------------------------------------
__global__ void setup_lam(const float* __restrict__ Lre_in,
                          const float* __restrict__ Lim_in,
                          const float* __restrict__ log_step,
                          float* __restrict__ lam) {
    int p = blockIdx.x * blockDim.x + threadIdx.x;
    if (p >= P_DIM) return;
    float step = expf(log_step[p]);
    float c = Lre_in[p];
    float d = Lim_in[p];
    float mag = expf(c * step);
    float ang = d * step;
    float lr = mag * cosf(ang);
    float li = mag * sinf(ang);
    float a = lr - 1.0f, b = li;
    float inv = 1.0f / (c * c + d * d);
    lam[p]             = lr;
    lam[P_DIM + p]     = li;
    lam[2 * P_DIM + p] = (a * c + b * d) * inv;   // g_re
    lam[3 * P_DIM + p] = (b * c - a * d) * inv;   // g_im
}

// Fused weight build.
// W1[n][k] bf16 (N2 x H): n<512 -> B_bar_re, n>=512 -> B_bar_im
// W2[h][k] bf16 (H x N2): k<512 -> 2*C_re,   k>=512 -> -2*C_im
__global__ void build_W(const float* __restrict__ B,
                        const float* __restrict__ C,
                        const float* __restrict__ lam,
                        unsigned short* __restrict__ W1,
                        unsigned short* __restrict__ W2) {
    int idx = blockIdx.x * blockDim.x + threadIdx.x;
    if (idx < P_DIM * H_DIM) {                       // W1 half: idx over P*H
        int p = idx >> 10;
        int h = idx & (H_DIM - 1);
        float bre = B[(size_t)idx * 2];
        float bim = B[(size_t)idx * 2 + 1];
        float gre = lam[2 * P_DIM + p];
        float gim = lam[3 * P_DIM + p];
        W1[(size_t)p * H_DIM + h]           = (unsigned short)f2bf_bits(gre * bre - gim * bim);
        W1[(size_t)(P_DIM + p) * H_DIM + h] = (unsigned short)f2bf_bits(gre * bim + gim * bre);
    } else {                                         // W2 half: idx over H*P
        int j = idx - P_DIM * H_DIM;
        int h = j >> 9;
        int p = j & (P_DIM - 1);
        float cre = C[(size_t)j * 2];
        float cim = C[(size_t)j * 2 + 1];
        W2[(size_t)h * N2 + p]         = (unsigned short)f2bf_bits( 2.0f * cre);
        W2[(size_t)h * N2 + P_DIM + p] = (unsigned short)f2bf_bits(-2.0f * cim);
    }
}

__global__ void convert_sig(const float* __restrict__ in,
                            unsigned short* __restrict__ out) {
    size_t i = ((size_t)blockIdx.x * 256 + threadIdx.x) * 4;
    float4 v = *(const float4*)(in + i);
    ushort4 o;
    o.x = (unsigned short)f2bf_bits(v.x);
    o.y = (unsigned short)f2bf_bits(v.y);
    o.z = (unsigned short)f2bf_bits(v.z);
    o.w = (unsigned short)f2bf_bits(v.w);
    *(ushort4*)(out + i) = o;
}

// ---------------------------------------------------------------------------
// bf16 MFMA GEMM. Out[m][n] = sum_k A[m][k]*W[n][k].
// A: M x K bf16 row-major, W: N x K bf16 row-major (K = 1024).
// Block tile 128(m) x 128(n), BK=64, LDS 32 KB. 256 thr = 4 waves in 2x2;
// wave tile 64x64 = 4x4 frags of 16x16x32 MFMA (verified layout).
// Grid 1024, __launch_bounds__(256,4) -> 4 blocks/CU (16 waves): barrier
// drains overlap across blocks (round-5 limit was 2 blocks/CU).
// LDS k-slot swizzle (round 5): slot' = (slot + (row>>1)) & 7, implemented
// by rotating the *global* source quad per lane at stage time (same 128 B
// segment -> coalescing + wave-uniform-dest preserved). Fragment reads
// touch each bank exactly 2x (free per m136).
// XCD swizzle: XCD x owns m-blocks [16x, 16x+16); 8 n-blocks consecutive.
// MODE 0: bf16 out via LDS-transposed coalesced 16B stores (2 phases).
// MODE 1: f32 out, + D[col]*bf2f(SigBf[row][col]) fused.
// ---------------------------------------------------------------------------
template <int MODE>
__global__ __launch_bounds__(256, 4) void gemm_mfma(
    const unsigned short* __restrict__ A,
    const unsigned short* __restrict__ W,
    void* __restrict__ Out, int K,
    const float* __restrict__ Dvec, const unsigned short* __restrict__ SigBf)
{
    __shared__ unsigned short smem[128 * 64 * 2];   // As 16K | Ws 16K
    unsigned short* As = smem;
    unsigned short* Ws = smem + 128 * 64;

    const int tid  = threadIdx.x;
    const int lane = tid & 63;
    const int wid  = tid >> 6;
    const int wm   = wid >> 1;     // 0..1
    const int wn   = wid & 1;      // 0..1

    // XCD swizzle: 128 m-blocks x 8 n-blocks, XCD x -> m-blocks [16x,16x+16)
    const int id  = blockIdx.x;
    const int xcd = id & 7;
    const int j   = id >> 3;              // 0..127
    const int mb  = xcd * 16 + (j >> 3);  // m-block (128 rows)
    const int nb  = j & 7;                // n-block (128 cols)
    const int m0 = mb * 128;
    const int n0 = nb * 128;

    // --- staging geometry (swizzled) --------------------------------------
    // chunk c (16 B): row = c>>3, slot = c&7; slot holds global quad
    // qg = (slot - (row>>1)) & 7. For c = i*256 + tid (i*32 rows, i*16%8==0):
    const int srow = tid >> 3;                                  // 0..31
    const int qg   = ((tid & 7) - ((tid >> 4) & 7)) & 7;        // const/lane
    const unsigned short* Abase = A + (size_t)(m0 + srow) * K + qg * 8;
    const unsigned short* Wbase = W + (size_t)(n0 + srow) * K + qg * 8;

    const int fr = lane & 15;        // m-row / n-col within 16
    const int fq = (lane >> 4) & 3;  // k-quad within 32
    const int sw = fr >> 1;          // swizzle rotation for this lane

    f32x4 acc[4][4] = {};

    for (int k0 = 0; k0 < K; k0 += 64) {
        __syncthreads();
        #pragma unroll
        for (int i = 0; i < 4; ++i)      // A: 1024 chunks (128 rows x 8 slots)
            ASYNC_COPY16(Abase + (size_t)(i * 32) * K + k0,
                         As + (size_t)(i * 256 + wid * 64) * 8);
        #pragma unroll
        for (int i = 0; i < 4; ++i)      // W: 1024 chunks
            ASYNC_COPY16(Wbase + (size_t)(i * 32) * K + k0,
                         Ws + (size_t)(i * 256 + wid * 64) * 8);
        __syncthreads();

        #pragma unroll
        for (int kk = 0; kk < 2; ++kk) {
            bf16x8 af[4], wf[4];
            #pragma unroll
            for (int mi = 0; mi < 4; ++mi) {
                int row = wm * 64 + mi * 16 + fr;
                int sl  = (kk * 4 + fq + sw) & 7;
                af[mi] = *(const bf16x8*)&As[(size_t)row * 64 + sl * 8];
            }
            #pragma unroll
            for (int ni = 0; ni < 4; ++ni) {
                int row = wn * 64 + ni * 16 + fr;
                int sl  = (kk * 4 + fq + sw) & 7;
                wf[ni] = *(const bf16x8*)&Ws[(size_t)row * 64 + sl * 8];
            }
            #pragma unroll
            for (int mi = 0; mi < 4; ++mi)
                #pragma unroll
                for (int ni = 0; ni < 4; ++ni)
                    acc[mi][ni] = __builtin_amdgcn_mfma_f32_16x16x32_bf16(
                        af[mi], wf[ni], acc[mi][ni], 0, 0, 0);
        }
    }

    // C/D layout (m89): col = lane&15, row = (lane>>4)*4 + reg
    if (MODE == 0) {
        // bf16 out: transpose through LDS (two 64x128 half-tiles, 16 KB)
        unsigned short* T = smem;
        #pragma unroll
        for (int h = 0; h < 2; ++h) {
            __syncthreads();       // prior LDS readers done
            if (wm == h) {
                #pragma unroll
                for (int mi = 0; mi < 4; ++mi)
                    #pragma unroll
                    for (int ni = 0; ni < 4; ++ni)
                        #pragma unroll
                        for (int r = 0; r < 4; ++r) {
                            int lrow = mi * 16 + fq * 4 + r;      // 0..63
                            int lcol = wn * 64 + ni * 16 + fr;    // 0..127
                            T[lrow * 128 + lcol] =
                                (unsigned short)f2bf_bits(acc[mi][ni][r]);
                        }
            }
            __syncthreads();
            // 64 rows x 128 cols = 1024 chunks of 8 ushorts (16 B)
            #pragma unroll
            for (int jj = 0; jj < 4; ++jj) {
                int chunk = jj * 256 + tid;        // 0..1023
                int row = chunk >> 4;              // 0..63
                int co  = (chunk & 15) * 8;        // 0..120
                *(ulonglong2*)((unsigned short*)Out +
                    (size_t)(m0 + h * 64 + row) * 1024 + n0 + co) =
                    *(const ulonglong2*)&T[row * 128 + co];
            }
        }
    } else {
        float Dl[4];
        #pragma unroll
        for (int ni = 0; ni < 4; ++ni)
            Dl[ni] = Dvec[n0 + wn * 64 + ni * 16 + fr];
        #pragma unroll
        for (int mi = 0; mi < 4; ++mi) {
            #pragma unroll
            for (int ni = 0; ni < 4; ++ni) {
                #pragma unroll
                for (int r = 0; r < 4; ++r) {
                    int row = m0 + wm * 64 + mi * 16 + fq * 4 + r;
                    int col = n0 + wn * 64 + ni * 16 + fr;
                    float v = acc[mi][ni][r];
                    v = fmaf(Dl[ni], bf2f(SigBf[(size_t)row * 1024 + col]), v);
                    ((float*)Out)[(size_t)row * 1024 + col] = v;
                }
            }
        }
    }
}

// ---------------------------------------------------------------------------
// Scan pass A: per (b, chunk) local scan (zero init) -> chunk-end sums.
// ---------------------------------------------------------------------------
__global__ __launch_bounds__(256) void scan_sums(
    const unsigned short* __restrict__ Bu, const float* __restrict__ lam,
    float* __restrict__ S)
{
    int b = blockIdx.x, c = blockIdx.y, t = threadIdx.x;
    int p0 = 2 * t, p1 = 2 * t + 1;
    float lr0 = lam[p0], li0 = lam[P_DIM + p0];
    float lr1 = lam[p1], li1 = lam[P_DIM + p1];
    const unsigned* base =
        (const unsigned*)(Bu + ((size_t)b * L_SEQ + (size_t)c * T_CHUNK) * N2);
    float xr0 = 0, xi0 = 0, xr1 = 0, xi1 = 0;
    for (int j0 = 0; j0 < T_CHUNK; j0 += 8) {
        unsigned R[8], I[8];
        #pragma unroll
        for (int j = 0; j < 8; ++j) {
            R[j] = base[(size_t)(j0 + j) * 512 + t];
            I[j] = base[(size_t)(j0 + j) * 512 + 256 + t];
        }
        #pragma unroll
        for (int j = 0; j < 8; ++j) {
            float nr0 = fmaf(lr0, xr0, fmaf(-li0, xi0, bf_lo(R[j])));
            float ni0 = fmaf(lr0, xi0, fmaf( li0, xr0, bf_lo(I[j])));
            float nr1 = fmaf(lr1, xr1, fmaf(-li1, xi1, bf_hi(R[j])));
            float ni1 = fmaf(lr1, xi1, fmaf( li1, xr1, bf_hi(I[j])));
            xr0 = nr0; xi0 = ni0; xr1 = nr1; xi1 = ni1;
        }
    }
    float* Sb = S + ((size_t)(b * NC + c) * 2) * P_DIM;
    Sb[p0] = xr0; Sb[p1] = xr1;
    Sb[P_DIM + p0] = xi0; Sb[P_DIM + p1] = xi1;
}

// Pass B: carries. cin[b][0]=0; cin[c] = lam^T_CHUNK * cin[c-1] + S[c-1].
__global__ __launch_bounds__(512) void scan_carry(
    const float* __restrict__ S, const float* __restrict__ lam,
    float* __restrict__ CIN)
{
    int b = blockIdx.x, p = threadIdx.x;
    float lr = lam[p], li = lam[P_DIM + p];
    float pr = lr, pi = li;                 // lam^64 via 6 squarings
    #pragma unroll
    for (int i = 0; i < 6; ++i) {
        float nr = pr * pr - pi * pi;
        float ni = 2.0f * pr * pi;
        pr = nr; pi = ni;
    }
    float cr = 0, ci = 0;
    for (int c = 0; c < NC; ++c) {
        float* Cb = CIN + ((size_t)(b * NC + c) * 2) * P_DIM;
        Cb[p] = cr; Cb[P_DIM + p] = ci;
        const float* Sb = S + ((size_t)(b * NC + c) * 2) * P_DIM;
        float sr = Sb[p], si = Sb[P_DIM + p];
        float nr = fmaf(pr, cr, fmaf(-pi, ci, sr));
        float ni = fmaf(pr, ci, fmaf( pi, cr, si));
        cr = nr; ci = ni;
    }
}

// Pass C: x = cin; x = lam*x + u; overwrite Bu with xs (bf16); emit state.
__global__ __launch_bounds__(256) void scan_apply(
    unsigned short* __restrict__ Bu, const float* __restrict__ lam,
    const float* __restrict__ CIN, float* __restrict__ out_state,
    int interleaved)
{
    int b = blockIdx.x, c = blockIdx.y, t = threadIdx.x;
    int p0 = 2 * t, p1 = 2 * t + 1;
    float lr0 = lam[p0], li0 = lam[P_DIM + p0];
    float lr1 = lam[p1], li1 = lam[P_DIM + p1];
    const float* Cb = CIN + ((size_t)(b * NC + c) * 2) * P_DIM;
    float xr0 = Cb[p0], xi0 = Cb[P_DIM + p0];
    float xr1 = Cb[p1], xi1 = Cb[P_DIM + p1];
    unsigned* base =
        (unsigned*)(Bu + ((size_t)b * L_SEQ + (size_t)c * T_CHUNK) * N2);
    for (int j0 = 0; j0 < T_CHUNK; j0 += 8) {
        unsigned R[8], I[8];
        #pragma unroll
        for (int j = 0; j < 8; ++j) {
            R[j] = base[(size_t)(j0 + j) * 512 + t];
            I[j] = base[(size_t)(j0 + j) * 512 + 256 + t];
        }
        #pragma unroll
        for (int j = 0; j < 8; ++j) {
            float nr0 = fmaf(lr0, xr0, fmaf(-li0, xi0, bf_lo(R[j])));
            float ni0 = fmaf(lr0, xi0, fmaf( li0, xr0, bf_lo(I[j])));
            float nr1 = fmaf(lr1, xr1, fmaf(-li1, xi1, bf_hi(R[j])));
            float ni1 = fmaf(lr1, xi1, fmaf( li1, xr1, bf_hi(I[j])));
            xr0 = nr0; xi0 = ni0; xr1 = nr1; xi1 = ni1;
            R[j] = f2bf_bits(nr0) | (f2bf_bits(nr1) << 16);
            I[j] = f2bf_bits(ni0) | (f2bf_bits(ni1) << 16);
        }
        #pragma unroll
        for (int j = 0; j < 8; ++j) {
            base[(size_t)(j0 + j) * 512 + t]       = R[j];
            base[(size_t)(j0 + j) * 512 + 256 + t] = I[j];
        }
    }
    if (c == NC - 1) {
        if (interleaved) {
            out_state[((size_t)b * P_DIM + p0) * 2]     = xr0;
            out_state[((size_t)b * P_DIM + p0) * 2 + 1] = xi0;
            out_state[((size_t)b * P_DIM + p1) * 2]     = xr1;
            out_state[((size_t)b * P_DIM + p1) * 2 + 1] = xi1;
        } else {
            out_state[(size_t)b * P_DIM + p0] = xr0;
            out_state[(size_t)b * P_DIM + p1] = xr1;
        }
    }
}

// ---------------------------------------------------------------------------
extern "C" void kernel_launch(void* const* d_in, const int* in_sizes, int n_in,
                              void* d_out, int out_size, void* d_ws, size_t ws_size,
                              hipStream_t stream)
{
    const float* signal   = (const float*)d_in[0];
    // d_in[1] = prev_state: never reaches the scan's b-component -> no effect
    const float* Lre      = (const float*)d_in[2];
    const float* Lim      = (const float*)d_in[3];
    const float* B        = (const float*)d_in[4];
    const float* C        = (const float*)d_in[5];
    const float* Dv       = (const float*)d_in[6];
    const float* log_step = (const float*)d_in[7];

    // ws layout (bytes)
    char* ws = (char*)d_ws;
    unsigned short* sigbf = (unsigned short*)ws;                      // 32 MB
    unsigned short* Bubf  = (unsigned short*)(ws + 33554432);         // 32 MB
    unsigned short* W1bf  = (unsigned short*)(ws + 67108864);         // 2 MB
    unsigned short* W2bf  = (unsigned short*)(ws + 69206016);         // 2 MB
    float*          lam   = (float*)(ws + 71303168);                  // 8 KB
    float*          S     = (float*)(ws + 71311360);                  // 512 KB
    float*          CIN   = (float*)(ws + 71835648);                  // 512 KB
    size_t need = 72359936;
    if (ws_size < need) return;

    float* y_out = (float*)d_out;
    float* state_out = y_out + (size_t)M_DIM * H_DIM;
    int interleaved = (out_size - M_DIM * H_DIM) >= 2 * BATCH_N * P_DIM;

    setup_lam<<<dim3(2), dim3(256), 0, stream>>>(Lre, Lim, log_step, lam);
    build_W<<<dim3((2 * P_DIM * H_DIM) / 256), dim3(256), 0, stream>>>(
        B, C, lam, W1bf, W2bf);
    convert_sig<<<dim3((M_DIM * H_DIM) / 1024), dim3(256), 0, stream>>>(signal, sigbf);

    // GEMM1: Bu[m][n] = sum_h sig[m][h] * W1[n][h]   (bf16 out)
    gemm_mfma<0><<<dim3(1024), dim3(256), 0, stream>>>(
        sigbf, W1bf, Bubf, H_DIM, nullptr, nullptr);

    scan_sums<<<dim3(BATCH_N, NC), dim3(256), 0, stream>>>(Bubf, lam, S);
    scan_carry<<<dim3(BATCH_N), dim3(512), 0, stream>>>(S, lam, CIN);
    scan_apply<<<dim3(BATCH_N, NC), dim3(256), 0, stream>>>(
        Bubf, lam, CIN, state_out, interleaved);

    // GEMM2: y[m][h] = sum_k xs[m][k]*W2[h][k] + D[h]*sig[m][h]  (fp32 out)
    gemm_mfma<1><<<dim3(1024), dim3(256), 0, stream>>>(
        Bubf, W2bf, y_out, N2, Dv, sigbf);
}